// Round 4
// baseline (371.940 us; speedup 1.0000x reference)
//
#include <hip/hip_runtime.h>
#include <math.h>

#define HW2 262144              // 512*512
#define TWO_PI     6.28318530717958647693f
#define INV_TWO_PI 0.15915494309189533577f
#define LOG2E      1.44269504088896340736f

typedef float f32x16 __attribute__((ext_vector_type(16)));

// compile-time for -> all h/nh indices constexpr -> vector extract/insert
// with constant lane (SSA values, cannot be demoted to scratch).
// R1-R3: float h[64] alloca stayed memory-backed (VGPR_Count=72, dur 290us,
// VALUBusy 52% from reload->fmac chains). f32x16 x4 forces VGPR residency.
template <int I> struct ic { static constexpr int v = I; };
template <int I, int N, typename F>
__device__ __forceinline__ void sfor(F&& f) {
    if constexpr (I < N) { f(ic<I>{}); sfor<I + 1, N>(f); }
}

// Per-(layer,channel) folded gabor constants, 8 floats each:
// [A, B, C, mu0, mu1, w0/2pi, w1/2pi, b/2pi]
// g = exp2(A*d0^2 + B*d0*d1 + C*d1^2),  d = x - mu
// sin term = v_sin(w0r*x0 + w1r*x1 + br)   (v_sin takes revolutions)
__global__ void gabor_precompute(const float* __restrict__ filt_w,
                                 const float* __restrict__ filt_b,
                                 const float* __restrict__ mu,
                                 const float* __restrict__ gamma,
                                 const float* __restrict__ theta,
                                 float* __restrict__ pc) {
    int i = blockIdx.x * blockDim.x + threadIdx.x;   // 0 .. 319  (= l*64 + c)
    if (i >= 5 * 64) return;
    float ang = TWO_PI * theta[i];
    float cs = cosf(ang), sn = sinf(ang);
    float g0 = gamma[i * 2 + 0], g1 = gamma[i * 2 + 1];
    float g0s = g0 * g0, g1s = g1 * g1;
    float cs2 = cs * cs, sn2 = sn * sn;
    float A = -0.5f * LOG2E * (g0s * cs2 + g1s * sn2);
    float Bq = -LOG2E * (cs * sn * (g0s - g1s));
    float Cq = -0.5f * LOG2E * (g0s * sn2 + g1s * cs2);
    float* o = pc + i * 8;
    o[0] = A;  o[1] = Bq; o[2] = Cq;
    o[3] = mu[i * 2 + 0];
    o[4] = mu[i * 2 + 1];
    o[5] = filt_w[i * 2 + 0] * INV_TWO_PI;
    o[6] = filt_w[i * 2 + 1] * INV_TWO_PI;
    o[7] = filt_b[i] * INV_TWO_PI;
}

__device__ __forceinline__ float gabor_eval(const float* __restrict__ q,
                                            float x0, float x1) {
    float d0 = x0 - q[3];
    float d1 = x1 - q[4];
    float t  = fmaf(q[0] * d0, d0, fmaf(q[1] * d0, d1, q[2] * d1 * d1));
    float e  = __builtin_amdgcn_exp2f(t);
    float sarg = fmaf(q[5], x0, fmaf(q[6], x1, q[7]));
    return e * __builtin_amdgcn_sinf(sarg);
}

__global__ __launch_bounds__(256, 2) void gabor_main(
    const float* __restrict__ x, const float* __restrict__ lin_w,
    const float* __restrict__ lin_b, const float* __restrict__ out_w,
    const float* __restrict__ out_b, const float* __restrict__ pc,
    float* __restrict__ out) {
    int p   = blockIdx.x * 256 + threadIdx.x;   // 0 .. 524287
    int b   = p >> 18;                          // pixel batch
    int pix = p & (HW2 - 1);
    const float* xb = x + b * (2 * HW2) + pix;
    float x0 = xb[0];
    float x1 = xb[HW2];

    f32x16 h[4];   // 64 hidden activations, static-indexed -> VGPR-resident
    sfor<0, 64>([&](auto C) {
        constexpr int c = C.v;
        h[c / 16][c % 16] = gabor_eval(pc + c * 8, x0, x1);
    });

#pragma unroll 1
    for (int l = 1; l <= 4; ++l) {
        const float* W  = lin_w + (l - 1) * 4096;
        const float* Bv = lin_b + (l - 1) * 64;
        const float* Q  = pc + l * 512;
        f32x16 nh[4];
        sfor<0, 64>([&](auto C) {
            constexpr int c = C.v;
            const float* wr = W + c * 64;
            // two accumulator chains: 2-cyc issue x 2 covers 4-cyc dep latency
            float a0 = Bv[c];
            float a1 = 0.0f;
            sfor<0, 32>([&](auto K) {
                constexpr int k0 = 2 * K.v;
                constexpr int k1 = 2 * K.v + 1;
                a0 = fmaf(wr[k0], h[k0 / 16][k0 % 16], a0);
                a1 = fmaf(wr[k1], h[k1 / 16][k1 % 16], a1);
            });
            nh[c / 16][c % 16] = gabor_eval(Q + c * 8, x0, x1) * (a0 + a1);
        });
        sfor<0, 4>([&](auto I) { h[I.v] = nh[I.v]; });
    }

    float* ob = out + b * (3 * HW2) + pix;
    sfor<0, 3>([&](auto O) {
        constexpr int o = O.v;
        const float* wr = out_w + o * 64;
        float a0 = out_b[o];
        float a1 = 0.0f;
        sfor<0, 32>([&](auto K) {
            constexpr int k0 = 2 * K.v;
            constexpr int k1 = 2 * K.v + 1;
            a0 = fmaf(wr[k0], h[k0 / 16][k0 % 16], a0);
            a1 = fmaf(wr[k1], h[k1 / 16][k1 % 16], a1);
        });
        ob[o * HW2] = a0 + a1;
    });
}

extern "C" void kernel_launch(void* const* d_in, const int* in_sizes, int n_in,
                              void* d_out, int out_size, void* d_ws, size_t ws_size,
                              hipStream_t stream) {
    const float* x      = (const float*)d_in[0];
    const float* filt_w = (const float*)d_in[1];
    const float* filt_b = (const float*)d_in[2];
    const float* mu     = (const float*)d_in[3];
    const float* gamma  = (const float*)d_in[4];
    const float* theta  = (const float*)d_in[5];
    const float* lin_w  = (const float*)d_in[6];
    const float* lin_b  = (const float*)d_in[7];
    const float* out_w  = (const float*)d_in[8];
    const float* out_b  = (const float*)d_in[9];
    float* pc = (float*)d_ws;   // 5*64*8 floats = 10 KB

    gabor_precompute<<<1, 320, 0, stream>>>(filt_w, filt_b, mu, gamma, theta, pc);
    gabor_main<<<2048, 256, 0, stream>>>(x, lin_w, lin_b, out_w, out_b, pc,
                                         (float*)d_out);
}

// Round 5
// 149.000 us; speedup vs baseline: 2.4962x; 2.4962x over previous
//
#include <hip/hip_runtime.h>
#include <hip/hip_bf16.h>
#include <math.h>

#define HW2 262144              // 512*512
#define TWO_PI     6.28318530717958647693f
#define INV_TWO_PI 0.15915494309189533577f
#define LOG2E      1.44269504088896340736f

typedef float  f32x4  __attribute__((ext_vector_type(4)));
typedef float  f32x8  __attribute__((ext_vector_type(8)));
typedef short  s16x8  __attribute__((ext_vector_type(8)));
typedef short  s16x4  __attribute__((ext_vector_type(4)));
typedef unsigned short ushort_t;

template <int I> struct ic { static constexpr int v = I; };
template <int I, int N, typename F>
__device__ __forceinline__ void sfor(F&& f) {
    if constexpr (I < N) { f(ic<I>{}); sfor<I + 1, N>(f); }
}

__device__ __forceinline__ ushort_t bf16_hi(float v) {
    __hip_bfloat16 h = __float2bfloat16(v);
    return __builtin_bit_cast(ushort_t, h);
}
__device__ __forceinline__ float bf16_tof(ushort_t u) {
    unsigned int x = ((unsigned int)u) << 16;
    return __builtin_bit_cast(float, x);
}

// ---- ws layout (bytes) ----
// pcq    f32[5][64][8]  @ 0      gabor quadratic constants
// whi    u16[4][64][64] @ 10240  lin_w hi-bf16, row-major [c_out][k]
// wlo    u16[4][64][64] @ 43008  lin_w lo-bf16
// wouthi u16[16][64]    @ 75776  out_w hi (rows 3..15 zero)
// woutlo u16[16][64]    @ 77824
#define WS_WHI  10240
#define WS_WLO  43008
#define WS_WOH  75776
#define WS_WOL  77824

__global__ void gabor_pre(const float* __restrict__ filt_w,
                          const float* __restrict__ filt_b,
                          const float* __restrict__ mu,
                          const float* __restrict__ gamma,
                          const float* __restrict__ theta,
                          const float* __restrict__ lin_w,
                          const float* __restrict__ out_w,
                          float* __restrict__ pcq,
                          ushort_t* __restrict__ whi, ushort_t* __restrict__ wlo,
                          ushort_t* __restrict__ wouthi, ushort_t* __restrict__ woutlo) {
    int t = blockIdx.x * 256 + threadIdx.x;
    if (t < 320) {
        int i = t;
        float ang = TWO_PI * theta[i];
        float cs = cosf(ang), sn = sinf(ang);
        float g0 = gamma[i*2+0], g1 = gamma[i*2+1];
        float g0s = g0*g0, g1s = g1*g1;
        float cs2 = cs*cs, sn2 = sn*sn;
        float* o = pcq + i*8;
        o[0] = -0.5f * LOG2E * (g0s*cs2 + g1s*sn2);
        o[1] = -LOG2E * (cs*sn*(g0s - g1s));
        o[2] = -0.5f * LOG2E * (g0s*sn2 + g1s*cs2);
        o[3] = mu[i*2+0];
        o[4] = mu[i*2+1];
        o[5] = filt_w[i*2+0] * INV_TWO_PI;
        o[6] = filt_w[i*2+1] * INV_TWO_PI;
        o[7] = filt_b[i] * INV_TWO_PI;
    } else if (t < 320 + 16384) {
        int i = t - 320;                       // l*4096 + c*64 + k
        float w = lin_w[i];
        ushort_t h = bf16_hi(w);
        whi[i] = h;
        wlo[i] = bf16_hi(w - bf16_tof(h));
    } else if (t < 320 + 16384 + 1024) {
        int i = t - (320 + 16384);             // m*64 + k
        int m = i >> 6;
        float w = (m < 3) ? out_w[i] : 0.0f;   // pad rows 3..15 with zeros
        ushort_t h = bf16_hi(w);
        wouthi[i] = h;
        woutlo[i] = bf16_hi(w - bf16_tof(h));
    }
}

// g*sin eval from folded constants qa=(A,B,C,mu0) qb=(mu1,w0r,w1r,br)
__device__ __forceinline__ float geval(f32x4 qa, f32x4 qb, float x0, float x1) {
    float d0 = x0 - qa[3];
    float d1 = x1 - qb[0];
    float t  = fmaf(qa[0]*d0, d0, fmaf(qa[1]*d0, d1, qa[2]*d1*d1));
    float e  = __builtin_amdgcn_exp2f(t);
    float sa = fmaf(qb[1], x0, fmaf(qb[2], x1, qb[3]));
    return e * __builtin_amdgcn_sinf(sa);
}

// One wave (64 threads) = 64 pixels. GEMM per layer: D[c,px] = W[c,k] h[k,px]
// via mfma_f32_16x16x32_bf16, split-bf16 (4 products, f32-exact).
// Layouts (verified m89/m91/m97 pattern):
//   A frag: m = lane&15, k = (lane>>4)*8 + j, 8 contiguous k (b128)
//   B frag: n = lane&15, k = (lane>>4)*8 + j, loaded from [px][k] rows (B^T style)
//   C/D:    col n = lane&15, row m = (lane>>4)*4 + reg
// h LDS: 2 planes (hi 0..8191, lo 8192..16383), [px][c] bf16 rows of 128B,
// 16B-block XOR swizzle: block' = block ^ (px&7)  (uniform banks).
__global__ __launch_bounds__(64, 2) void gabor_mfma(
    const float* __restrict__ x, const float* __restrict__ lin_b,
    const float* __restrict__ out_b, const float* __restrict__ pcq,
    const ushort_t* __restrict__ whi, const ushort_t* __restrict__ wlo,
    const ushort_t* __restrict__ wouthi, const ushort_t* __restrict__ woutlo,
    float* __restrict__ out) {
    __shared__ __attribute__((aligned(16))) unsigned char hbuf[16384];
    const int lane = threadIdx.x;
    const int g    = lane >> 4;
    const int lm   = lane & 15;
    const int base = blockIdx.x * 64;

    f32x4 x0v, x1v;
    int pixo[4];
    sfor<0, 4>([&](auto NI) {
        int P  = base + NI.v*16 + lm;
        int bb = P >> 18, pix = P & (HW2 - 1);
        const float* xb = x + bb*(2*HW2) + pix;
        x0v[NI.v] = xb[0];
        x1v[NI.v] = xb[HW2];
        pixo[NI.v] = bb*(3*HW2) + pix;
    });

    // ---- layer 0: h0 = gabor, computed directly at B-frag positions ----
    sfor<0, 2>([&](auto KC) {
        f32x8 vv[4];
        sfor<0, 8>([&](auto J) {
            const float* q = pcq + (KC.v*32 + g*8 + J.v)*8;
            f32x4 qa = *(const f32x4*)q, qb = *(const f32x4*)(q + 4);
            sfor<0, 4>([&](auto NI) {
                vv[NI.v][J.v] = geval(qa, qb, x0v[NI.v], x1v[NI.v]);
            });
        });
        sfor<0, 4>([&](auto NI) {
            s16x8 fh, fl;
            sfor<0, 8>([&](auto J) {
                float v = vv[NI.v][J.v];
                ushort_t h = bf16_hi(v);
                fh[J.v] = (short)h;
                fl[J.v] = (short)bf16_hi(v - bf16_tof(h));
            });
            int px  = NI.v*16 + lm;
            int blk = (4*KC.v + g) ^ (px & 7);
            char* p0 = (char*)hbuf + px*128 + blk*16;
            *(s16x8*)(p0)        = fh;
            *(s16x8*)(p0 + 8192) = fl;
        });
    });

    // ---- layers 1..4: nh = gabor * (W h + b) ----
#pragma unroll 1
    for (int l = 1; l <= 4; ++l) {
        __syncthreads();
        const ushort_t* whl = whi + (l-1)*4096;
        const ushort_t* wll = wlo + (l-1)*4096;
        const float*    bv  = lin_b + (l-1)*64;
        f32x4 acc[4][4];
        sfor<0, 4>([&](auto MI) {
            f32x4 bias = *(const f32x4*)(bv + MI.v*16 + 4*g);
            sfor<0, 4>([&](auto NI) { acc[MI.v][NI.v] = bias; });
        });
        sfor<0, 2>([&](auto KC) {
            s16x8 bh[4], bl[4];
            sfor<0, 4>([&](auto NI) {
                int px  = NI.v*16 + lm;
                int blk = (4*KC.v + g) ^ (px & 7);
                const char* p0 = (const char*)hbuf + px*128 + blk*16;
                bh[NI.v] = *(const s16x8*)(p0);
                bl[NI.v] = *(const s16x8*)(p0 + 8192);
            });
            sfor<0, 4>([&](auto MI) {
                int off = (MI.v*16 + lm)*64 + KC.v*32 + g*8;
                s16x8 ah = *(const s16x8*)(whl + off);
                s16x8 al = *(const s16x8*)(wll + off);
                sfor<0, 4>([&](auto NI) {
                    f32x4 a = acc[MI.v][NI.v];
                    a = __builtin_amdgcn_mfma_f32_16x16x32_bf16(ah, bh[NI.v], a, 0, 0, 0);
                    a = __builtin_amdgcn_mfma_f32_16x16x32_bf16(ah, bl[NI.v], a, 0, 0, 0);
                    a = __builtin_amdgcn_mfma_f32_16x16x32_bf16(al, bh[NI.v], a, 0, 0, 0);
                    a = __builtin_amdgcn_mfma_f32_16x16x32_bf16(al, bl[NI.v], a, 0, 0, 0);
                    acc[MI.v][NI.v] = a;
                });
            });
        });
        __syncthreads();
        const float* pcl = pcq + l*512;
        sfor<0, 4>([&](auto MI) {
            f32x4 vo[4];
            sfor<0, 4>([&](auto R) {
                const float* q = pcl + (MI.v*16 + 4*g + R.v)*8;
                f32x4 qa = *(const f32x4*)q, qb = *(const f32x4*)(q + 4);
                sfor<0, 4>([&](auto NI) {
                    vo[NI.v][R.v] = geval(qa, qb, x0v[NI.v], x1v[NI.v])
                                    * acc[MI.v][NI.v][R.v];
                });
            });
            sfor<0, 4>([&](auto NI) {
                s16x4 fh, fl;
                sfor<0, 4>([&](auto R) {
                    float v = vo[NI.v][R.v];
                    ushort_t h = bf16_hi(v);
                    fh[R.v] = (short)h;
                    fl[R.v] = (short)bf16_hi(v - bf16_tof(h));
                });
                int px  = NI.v*16 + lm;
                int blk = (2*MI.v + (g >> 1)) ^ (px & 7);
                char* p0 = (char*)hbuf + px*128 + blk*16 + (g & 1)*8;
                *(s16x4*)(p0)        = fh;
                *(s16x4*)(p0 + 8192) = fl;
            });
        });
    }

    // ---- output: out[o,px] = Wout[o,k] h4[k,px] + out_b ----
    __syncthreads();
    f32x4 ao[4];
    sfor<0, 4>([&](auto NI) { ao[NI.v] = (f32x4)(0.0f); });
    sfor<0, 2>([&](auto KC) {
        s16x8 bh[4], bl[4];
        sfor<0, 4>([&](auto NI) {
            int px  = NI.v*16 + lm;
            int blk = (4*KC.v + g) ^ (px & 7);
            const char* p0 = (const char*)hbuf + px*128 + blk*16;
            bh[NI.v] = *(const s16x8*)(p0);
            bl[NI.v] = *(const s16x8*)(p0 + 8192);
        });
        int off = lm*64 + KC.v*32 + g*8;
        s16x8 ah = *(const s16x8*)(wouthi + off);
        s16x8 al = *(const s16x8*)(woutlo + off);
        sfor<0, 4>([&](auto NI) {
            f32x4 a = ao[NI.v];
            a = __builtin_amdgcn_mfma_f32_16x16x32_bf16(ah, bh[NI.v], a, 0, 0, 0);
            a = __builtin_amdgcn_mfma_f32_16x16x32_bf16(ah, bl[NI.v], a, 0, 0, 0);
            a = __builtin_amdgcn_mfma_f32_16x16x32_bf16(al, bh[NI.v], a, 0, 0, 0);
            a = __builtin_amdgcn_mfma_f32_16x16x32_bf16(al, bl[NI.v], a, 0, 0, 0);
            ao[NI.v] = a;
        });
    });
    if (lane < 16) {   // rows 0..3 live on g==0; out channels = rows 0..2
        float ob0 = out_b[0], ob1 = out_b[1], ob2 = out_b[2];
        sfor<0, 4>([&](auto NI) {
            float* po = out + pixo[NI.v];
            po[0]     = ao[NI.v][0] + ob0;
            po[HW2]   = ao[NI.v][1] + ob1;
            po[2*HW2] = ao[NI.v][2] + ob2;
        });
    }
}

extern "C" void kernel_launch(void* const* d_in, const int* in_sizes, int n_in,
                              void* d_out, int out_size, void* d_ws, size_t ws_size,
                              hipStream_t stream) {
    const float* x      = (const float*)d_in[0];
    const float* filt_w = (const float*)d_in[1];
    const float* filt_b = (const float*)d_in[2];
    const float* mu     = (const float*)d_in[3];
    const float* gamma  = (const float*)d_in[4];
    const float* theta  = (const float*)d_in[5];
    const float* lin_w  = (const float*)d_in[6];
    const float* lin_b  = (const float*)d_in[7];
    const float* out_w  = (const float*)d_in[8];
    const float* out_b  = (const float*)d_in[9];

    char* ws = (char*)d_ws;
    float*    pcq    = (float*)ws;
    ushort_t* whi    = (ushort_t*)(ws + WS_WHI);
    ushort_t* wlo    = (ushort_t*)(ws + WS_WLO);
    ushort_t* wouthi = (ushort_t*)(ws + WS_WOH);
    ushort_t* woutlo = (ushort_t*)(ws + WS_WOL);

    gabor_pre<<<70, 256, 0, stream>>>(filt_w, filt_b, mu, gamma, theta,
                                      lin_w, out_w, pcq, whi, wlo, wouthi, woutlo);
    gabor_mfma<<<8192, 64, 0, stream>>>(x, lin_b, out_b, pcq, whi, wlo,
                                        wouthi, woutlo, (float*)d_out);
}